// Round 11
// baseline (188.880 us; speedup 1.0000x reference)
//
#include <hip/hip_runtime.h>
#include <hip/hip_bf16.h>

// out[n,h,i,j] = logits[i][ clamp(j-i+512, 1, 1023) ],  logits = Q @ R  (per n,h)
// n=4 h=16 L=1024 d=64, table width 1025.
//
// R11 = R7 (best, 80.7 us) VERBATIM + two pure-store probe kernels into d_ws
// (268 MB each, nt): Probe0 mirrors the writer's exact addressing; Probe1 is
// linear. dur_us - 80.7 = t0 + t1 isolates whether the store pattern or the
// compute/store pacing is the 2x-off-roofline culprit.

#define NH 16
#define LQ 1024
#define DD 64
#define TT 1025
#define MAXP 512
#define PADS 4          // left pad in shorts (multiple of 4 keeps 8B alignment)
#define LSTRIDE2 1036   // shorts; row stride 2072 B

typedef float f32x4 __attribute__((ext_vector_type(4)));
typedef short s16x4 __attribute__((ext_vector_type(4)));
typedef short s16x8 __attribute__((ext_vector_type(8)));

__device__ __forceinline__ short f2bf(float f) {
    __hip_bfloat16 h = __float2bfloat16(f);   // RNE
    return __builtin_bit_cast(short, h);
}
__device__ __forceinline__ float bf2f(short s) {
    return __builtin_bit_cast(float, ((unsigned)(unsigned short)s) << 16);
}

// Writer helper: D = wave-uniform misalignment ((512 - i) & 3), compile-time.
template<int D>
__device__ __forceinline__ void write_chunks(const unsigned short* __restrict__ lrow,
                                             float p1, float p2,
                                             int i, int l, float* __restrict__ orow) {
    #pragma unroll
    for (int c = 0; c < 4; ++c) {
        const int j0 = c * 256 + 4 * l;
        const int t0 = j0 - i + MAXP;
        int colA = PADS + t0 - D;                 // = PADS + (t0 & ~3), 8B aligned
        colA = colA < 0 ? 0 : (colA > PADS + LQ ? PADS + LQ : colA);  // clamped lanes: value unused
        s16x4 A = *(const s16x4*)(lrow + colA);
        s16x4 B = {0, 0, 0, 0};
        if (D) B = *(const s16x4*)(lrow + colA + 4);
        f32x4 v;
        #pragma unroll
        for (int e = 0; e < 4; ++e) {
            const int t = t0 + e;
            const float in = bf2f((D + e < 4) ? A[D + e] : B[D + e - 4]);
            v[e] = t < 1 ? p1 : (t > LQ - 1 ? p2 : in);
        }
        __builtin_nontemporal_store(v, (f32x4*)(orow + j0));   // nt (R7/R8 A/B: +8%)
    }
}

// grid (ib=64, nh=64), block 256 = 4 waves; block = 16 i-rows x all 1024 t.
__global__ __launch_bounds__(256, 4) void lpb_fused(const float* __restrict__ Q,
                                                    const float* __restrict__ R,
                                                    float* __restrict__ out) {
    __shared__ unsigned short lg[16][LSTRIDE2];   // bf16 logits, 33.2 KB

    const int ib  = blockIdx.x;
    const int nh  = blockIdx.y;
    const int h   = nh & (NH - 1);
    const int tid = threadIdx.x;
    const int w   = tid >> 6, l = tid & 63;
    const int n   = l & 15, g = l >> 4;
    const int ibase = ib * 16;

    // Q fragment (op1/B of swapped MFMA): lane (n,g) holds Q[ibase+n][kh*32 + 8g + r]
    const float* qrow = Q + ((size_t)nh * LQ + (ibase + n)) * DD + 8 * g;
    s16x8 qf[2];
    #pragma unroll
    for (int kh = 0; kh < 2; ++kh) {
        f32x4 a = *(const f32x4*)(qrow + kh * 32);
        f32x4 b = *(const f32x4*)(qrow + kh * 32 + 4);
        #pragma unroll
        for (int r = 0; r < 4; ++r) { qf[kh][r] = f2bf(a[r]); qf[kh][4 + r] = f2bf(b[r]); }
    }

    // GEMM: wave w covers t in [256w, 256w+256), 16 tiles of 16 t, K=64
    const float* rbase = R + (size_t)(h * DD + 8 * g) * TT;
    #pragma unroll 4
    for (int mt = 0; mt < 16; ++mt) {
        const int tb = w * 256 + mt * 16;
        const float* rc = rbase + tb + n;
        s16x8 rf0, rf1;   // A: lane (n,g) holds R[h][8g+r][tb+n]  (row = t-local = n)
        #pragma unroll
        for (int r = 0; r < 8; ++r) {
            rf0[r] = f2bf(rc[(size_t)r * TT]);
            rf1[r] = f2bf(rc[(size_t)(32 + r) * TT]);
        }
        f32x4 acc = (f32x4){0.f, 0.f, 0.f, 0.f};
        acc = __builtin_amdgcn_mfma_f32_16x16x32_bf16(rf0, qf[0], acc, 0, 0, 0);
        acc = __builtin_amdgcn_mfma_f32_16x16x32_bf16(rf1, qf[1], acc, 0, 0, 0);
        // D: col = n -> i-local row, row = 4g+s -> t = tb+4g+s: pack to bf16, b64 write
        s16x4 hv;
        #pragma unroll
        for (int s = 0; s < 4; ++s) hv[s] = f2bf(acc[s]);
        *(s16x4*)&lg[n][PADS + tb + 4 * g] = hv;
    }
    __syncthreads();

    // writer: wave w emits rows 4w..4w+3 as full aligned 4KB rows (nt stores)
    #pragma unroll
    for (int rr = 0; rr < 4; ++rr) {
        const int il = 4 * w + rr;
        const int i  = ibase + il;
        const unsigned short* lrow = &lg[il][0];
        const float p1 = bf2f(lrow[PADS + 1]);          // left clamp constant
        const float p2 = bf2f(lrow[PADS + LQ - 1]);     // right clamp constant
        float* orow = out + ((size_t)nh * LQ + i) * LQ;
        switch ((MAXP - i) & 3) {                       // row-uniform shift
            case 0: write_chunks<0>(lrow, p1, p2, i, l, orow); break;
            case 1: write_chunks<1>(lrow, p1, p2, i, l, orow); break;
            case 2: write_chunks<2>(lrow, p1, p2, i, l, orow); break;
            default: write_chunks<3>(lrow, p1, p2, i, l, orow); break;
        }
    }
}

// ---- store-rate probes: write 64 KB of constants per block into d_ws (nt) ----
// PAT 0: byte-exact mirror of lpb_fused's writer addressing (16 rows of 4 KB,
//        wave w owns rows 4w..4w+3, 4 chunks of 1 KB each at 1 KB stride).
// PAT 1: same instruction count/width, fully linear (wave-contiguous 16 KB).
template<int PAT>
__global__ __launch_bounds__(256) void store_probe(float* __restrict__ dst, int nblk) {
    const int ib = blockIdx.x, nh = blockIdx.y;
    if (nh * 64 + ib >= nblk) return;
    const int tid = threadIdx.x;
    const int w = tid >> 6, l = tid & 63;
    const f32x4 v = {1.f, 2.f, 3.f, 4.f};
    if (PAT == 0) {
        #pragma unroll
        for (int rr = 0; rr < 4; ++rr) {
            const int i = nh * 1024 + ib * 16 + 4 * w + rr;   // global row, mirrors out[i]
            float* orow = dst + (size_t)i * 1024;
            #pragma unroll
            for (int c = 0; c < 4; ++c)
                __builtin_nontemporal_store(v, (f32x4*)(orow + c * 256 + 4 * l));
        }
    } else {
        float* base = dst + (size_t)(nh * 64 + ib) * 16384 + w * 4096;
        #pragma unroll
        for (int c = 0; c < 16; ++c)
            __builtin_nontemporal_store(v, (f32x4*)(base + c * 256 + 4 * l));
    }
}

extern "C" void kernel_launch(void* const* d_in, const int* in_sizes, int n_in,
                              void* d_out, int out_size, void* d_ws, size_t ws_size,
                              hipStream_t stream) {
    const float* Q = (const float*)d_in[0];
    const float* R = (const float*)d_in[1];
    float* out = (float*)d_out;

    lpb_fused<<<dim3(64, 64), 256, 0, stream>>>(Q, R, out);

    // probes: 268 MB of nt stores each into d_ws (capped by ws_size)
    const int nblk = (int)((ws_size / 65536) < 4096 ? (ws_size / 65536) : 4096);
    if (nblk > 0) {
        store_probe<0><<<dim3(64, 64), 256, 0, stream>>>((float*)d_ws, nblk);
        store_probe<1><<<dim3(64, 64), 256, 0, stream>>>((float*)d_ws, nblk);
    }
}

// Round 12
// 74.044 us; speedup vs baseline: 2.5509x; 2.5509x over previous
//
#include <hip/hip_runtime.h>
#include <hip/hip_bf16.h>

// out[n,h,i,j] = logits[i][ clamp(j-i+512, 1, 1023) ],  logits = Q @ R  (per n,h)
// n=4 h=16 L=1024 d=64, table width 1025.
//
// R12: producer/consumer wave specialization. Block = 4 waves, 2-slot LDS pipeline:
//   round r: waves 0-1 compute unit r (16 i-rows x 1024 t) into lg[r&1];
//            waves 2-3 stream unit r-1 from lg[(r-1)&1] to HBM (nt stores).
// Stores issue continuously instead of in post-barrier bursts (R11 probes showed
// pure-store rate 5 TB/s vs our 3.3 effective -> duty cycle was the gap).
// grid 512 = 2 blocks/CU exactly; 8 units/block; 9 rounds. XCD swizzle: 8 heads/XCD.

#define NH 16
#define LQ 1024
#define DD 64
#define TT 1025
#define MAXP 512
#define PADS 4          // left pad in shorts (multiple of 4 keeps 8B alignment)
#define LSTRIDE2 1036   // shorts; row stride 2072 B
#define UNITS 8

typedef float f32x4 __attribute__((ext_vector_type(4)));
typedef short s16x4 __attribute__((ext_vector_type(4)));
typedef short s16x8 __attribute__((ext_vector_type(8)));

__device__ __forceinline__ short f2bf(float f) {
    __hip_bfloat16 h = __float2bfloat16(f);   // RNE
    return __builtin_bit_cast(short, h);
}
__device__ __forceinline__ float bf2f(short s) {
    return __builtin_bit_cast(float, ((unsigned)(unsigned short)s) << 16);
}

// Writer helper: D = wave-uniform misalignment ((512 - i) & 3), compile-time.
template<int D>
__device__ __forceinline__ void write_chunks(const unsigned short* __restrict__ lrow,
                                             float p1, float p2,
                                             int i, int l, float* __restrict__ orow) {
    #pragma unroll
    for (int c = 0; c < 4; ++c) {
        const int j0 = c * 256 + 4 * l;
        const int t0 = j0 - i + MAXP;
        int colA = PADS + t0 - D;                 // = PADS + (t0 & ~3), 8B aligned
        colA = colA < 0 ? 0 : (colA > PADS + LQ ? PADS + LQ : colA);  // clamped lanes: value unused
        s16x4 A = *(const s16x4*)(lrow + colA);
        s16x4 B = {0, 0, 0, 0};
        if (D) B = *(const s16x4*)(lrow + colA + 4);
        f32x4 v;
        #pragma unroll
        for (int e = 0; e < 4; ++e) {
            const int t = t0 + e;
            const float in = bf2f((D + e < 4) ? A[D + e] : B[D + e - 4]);
            v[e] = t < 1 ? p1 : (t > LQ - 1 ? p2 : in);
        }
        __builtin_nontemporal_store(v, (f32x4*)(orow + j0));   // nt (R7/R8 A/B: +8%)
    }
}

// grid 512 (1D), block 256 = 4 waves (2 producers + 2 consumers), 8 units/block.
__global__ __launch_bounds__(256, 2) void lpb_pc(const float* __restrict__ Q,
                                                 const float* __restrict__ R,
                                                 float* __restrict__ out) {
    __shared__ unsigned short lg[2][16][LSTRIDE2];   // 2-slot pipeline, 66.3 KB

    // XCD-chunked bijective swizzle (512 % 8 == 0): XCD k gets nh in [8k, 8k+8)
    const int bidx = blockIdx.x;
    const int swz  = (bidx & 7) * 64 + (bidx >> 3);
    const int nh   = swz >> 3;
    const int ibg  = swz & 7;
    const int h    = nh & (NH - 1);

    const int tid = threadIdx.x;
    const int w = tid >> 6, l = tid & 63;
    const int n = l & 15, g = l >> 4;

    const float* rbase = R + (size_t)(h * DD + 8 * g) * TT;

    #pragma unroll 1
    for (int rnd = 0; rnd <= UNITS; ++rnd) {
        if (w < 2) {
            if (rnd < UNITS) {
                // ---- produce unit rnd into lg[rnd&1]: wave w covers t in [512w, 512w+512)
                const int ibase = (ibg * UNITS + rnd) * 16;
                const float* qrow = Q + ((size_t)nh * LQ + (ibase + n)) * DD + 8 * g;
                s16x8 qf[2];    // B-operand: lane (n,g) holds Q[ibase+n][kh*32 + 8g + r]
                #pragma unroll
                for (int kh = 0; kh < 2; ++kh) {
                    f32x4 a = *(const f32x4*)(qrow + kh * 32);
                    f32x4 b = *(const f32x4*)(qrow + kh * 32 + 4);
                    #pragma unroll
                    for (int e = 0; e < 4; ++e) { qf[kh][e] = f2bf(a[e]); qf[kh][4 + e] = f2bf(b[e]); }
                }
                unsigned short (*buf)[LSTRIDE2] = lg[rnd & 1];
                #pragma unroll 4
                for (int mt = 0; mt < 32; ++mt) {
                    const int tb = w * 512 + mt * 16;
                    const float* rc = rbase + tb + n;
                    s16x8 rf0, rf1;   // A-operand: lane (n,g) holds R[h][8g+e][tb+n]
                    #pragma unroll
                    for (int e = 0; e < 8; ++e) {
                        rf0[e] = f2bf(rc[(size_t)e * TT]);
                        rf1[e] = f2bf(rc[(size_t)(32 + e) * TT]);
                    }
                    f32x4 acc = (f32x4){0.f, 0.f, 0.f, 0.f};
                    acc = __builtin_amdgcn_mfma_f32_16x16x32_bf16(rf0, qf[0], acc, 0, 0, 0);
                    acc = __builtin_amdgcn_mfma_f32_16x16x32_bf16(rf1, qf[1], acc, 0, 0, 0);
                    // D: col=n -> i-local, row=4g+s -> t=tb+4g+s: pack bf16, b64 write
                    s16x4 hv;
                    #pragma unroll
                    for (int s = 0; s < 4; ++s) hv[s] = f2bf(acc[s]);
                    *(s16x4*)&buf[n][PADS + tb + 4 * g] = hv;
                }
            }
        } else {
            if (rnd > 0) {
                // ---- consume unit rnd-1 from lg[(rnd-1)&1]: wave (w-2) owns 8 rows
                const int u = rnd - 1;
                const int ibase = (ibg * UNITS + u) * 16;
                unsigned short (*buf)[LSTRIDE2] = lg[u & 1];
                const int cw = w - 2;
                #pragma unroll 1
                for (int rr = 0; rr < 8; ++rr) {
                    const int il = cw * 8 + rr;
                    const int i  = ibase + il;
                    const unsigned short* lrow = &buf[il][0];
                    const float p1 = bf2f(lrow[PADS + 1]);          // left clamp constant
                    const float p2 = bf2f(lrow[PADS + LQ - 1]);     // right clamp constant
                    float* orow = out + ((size_t)nh * LQ + i) * LQ;
                    switch ((MAXP - i) & 3) {                       // row-uniform shift
                        case 0: write_chunks<0>(lrow, p1, p2, i, l, orow); break;
                        case 1: write_chunks<1>(lrow, p1, p2, i, l, orow); break;
                        case 2: write_chunks<2>(lrow, p1, p2, i, l, orow); break;
                        default: write_chunks<3>(lrow, p1, p2, i, l, orow); break;
                    }
                }
            }
        }
        __syncthreads();   // orders: producer writes(rnd) -> consumer reads(rnd+1);
                           // consumer reads(rnd) -> producer overwrite(rnd+1)
    }
}

extern "C" void kernel_launch(void* const* d_in, const int* in_sizes, int n_in,
                              void* d_out, int out_size, void* d_ws, size_t ws_size,
                              hipStream_t stream) {
    const float* Q = (const float*)d_in[0];
    const float* R = (const float*)d_in[1];
    float* out = (float*)d_out;

    lpb_pc<<<dim3(512), 256, 0, stream>>>(Q, R, out);
}